// Round 1
// baseline (285.097 us; speedup 1.0000x reference)
//
#include <hip/hip_runtime.h>

#define S_LEN 4096
#define NROWS 16384   // B*S

typedef __attribute__((ext_vector_type(8))) __bf16 bf16x8;
typedef __attribute__((ext_vector_type(4))) float floatx4;

__device__ __forceinline__ unsigned short f2bf(float f) {
    unsigned int u = __float_as_uint(f);
    unsigned int r = (u + 0x7fffu + ((u >> 16) & 1u)) >> 16;
    return (unsigned short)r;
}

// ---------------- K1: QKV projection -> Q,K bf16 [row][64], V transposed bf16 [b][64][s]
__global__ __launch_bounds__(256) void qkv_kernel(
    const float* __restrict__ x,
    const float* __restrict__ Wq, const float* __restrict__ bq,
    const float* __restrict__ Wk, const float* __restrict__ bk,
    const float* __restrict__ Wv, const float* __restrict__ bv,
    unsigned short* __restrict__ Qb, unsigned short* __restrict__ Kb,
    unsigned short* __restrict__ Vt)
{
    __shared__ float xs[16 * 512];
    const int tid = threadIdx.x;
    const int row0 = blockIdx.x * 16;
    // stage 16 rows of x (32 KB) via float4
    {
        const float4* src = (const float4*)(x + (size_t)row0 * 512);
        float4* dst = (float4*)xs;
        #pragma unroll
        for (int i = 0; i < 8; i++) dst[tid + 256 * i] = src[tid + 256 * i];
    }
    __syncthreads();
    const int w = tid >> 6, lane = tid & 63;
    float accq[4] = {0.f, 0.f, 0.f, 0.f};
    float acck[4] = {0.f, 0.f, 0.f, 0.f};
    float accv[4] = {0.f, 0.f, 0.f, 0.f};
    const float* xrow = xs + (w * 4) * 512;
    #pragma unroll 4
    for (int kk = 0; kk < 512; kk++) {
        float wqv = Wq[kk * 64 + lane];
        float wkv = Wk[kk * 64 + lane];
        float wvv = Wv[kk * 64 + lane];
        #pragma unroll
        for (int r = 0; r < 4; r++) {
            float xv = xrow[r * 512 + kk];
            accq[r] = fmaf(xv, wqv, accq[r]);
            acck[r] = fmaf(xv, wkv, acck[r]);
            accv[r] = fmaf(xv, wvv, accv[r]);
        }
    }
    const float bqv = bq[lane], bkv = bk[lane], bvv = bv[lane];
    const int rowg = row0 + w * 4;
    #pragma unroll
    for (int r = 0; r < 4; r++) {
        Qb[(size_t)(rowg + r) * 64 + lane] = f2bf(accq[r] + bqv);
        Kb[(size_t)(rowg + r) * 64 + lane] = f2bf(acck[r] + bkv);
    }
    // V transposed: Vt[b][h=lane][s]; 4 consecutive s per lane -> one 8B store
    const int b = rowg >> 12;          // /4096
    const int s0 = rowg & 4095;
    unsigned short vp[4];
    #pragma unroll
    for (int r = 0; r < 4; r++) vp[r] = f2bf(accv[r] + bvv);
    *(uint2*)(void*)(Vt + ((size_t)b * 64 + lane) * S_LEN + s0) = *(const uint2*)vp;
}

// ---------------- K2: causal flash attention, bf16 MFMA, fp32 online softmax
__global__ __launch_bounds__(256) void attn_kernel(
    const unsigned short* __restrict__ Qb, const unsigned short* __restrict__ Kb,
    const unsigned short* __restrict__ Vt, float* __restrict__ Ous)
{
    __shared__ unsigned short Ks[64 * 72];   // [key][d], pad stride 72
    __shared__ unsigned short Vs[64 * 72];   // [d][key], pad stride 72
    __shared__ unsigned short Ps[4][16 * 72];
    const int tid = threadIdx.x;
    const int qt = blockIdx.x, b = blockIdx.y;
    const int q0 = qt * 64;
    const int w = tid >> 6, lane = tid & 63, cl = lane & 15, quad = lane >> 4;

    // A-fragments of Q (constant over k-loop): row = w*16+cl, k = quad*8..+7 (+32)
    const size_t qrow = (size_t)b * S_LEN + q0 + w * 16 + cl;
    const bf16x8 aq0 = *(const bf16x8*)(const void*)(Qb + qrow * 64 + quad * 8);
    const bf16x8 aq1 = *(const bf16x8*)(const void*)(Qb + qrow * 64 + 32 + quad * 8);

    float mrow[4], lrow[4];
    floatx4 Oacc[4];
    #pragma unroll
    for (int r = 0; r < 4; r++) { mrow[r] = -1e30f; lrow[r] = 0.f; }
    #pragma unroll
    for (int u = 0; u < 4; u++) Oacc[u] = (floatx4){0.f, 0.f, 0.f, 0.f};

    const float C2 = 0.022542110013890054f;  // log2(e)/sqrt(4096)

    for (int jt = 0; jt <= qt; jt++) {
        const int j0 = jt * 64;
        __syncthreads();  // prior iter's LDS reads complete before restage
        // stage K tile (natural) and V tile (from transposed V): 512 x 16B each
        {
            int c = tid;
            #pragma unroll
            for (int ii = 0; ii < 2; ii++, c += 256) {
                int row = c >> 3, c8 = c & 7;
                float4 kv = *(const float4*)(const void*)(Kb + ((size_t)b * S_LEN + j0 + row) * 64 + c8 * 8);
                *(float4*)(void*)(Ks + row * 72 + c8 * 8) = kv;
                float4 vv = *(const float4*)(const void*)(Vt + ((size_t)b * 64 + row) * S_LEN + j0 + c8 * 8);
                *(float4*)(void*)(Vs + row * 72 + c8 * 8) = vv;
            }
        }
        __syncthreads();

        // S = Q @ K^T : 4 key-subtiles x (K=64 as 2 chunks)
        floatx4 st[4];
        #pragma unroll
        for (int t = 0; t < 4; t++) {
            bf16x8 b0 = *(const bf16x8*)(const void*)(Ks + (t * 16 + cl) * 72 + quad * 8);
            bf16x8 b1 = *(const bf16x8*)(const void*)(Ks + (t * 16 + cl) * 72 + 32 + quad * 8);
            floatx4 acc = (floatx4){0.f, 0.f, 0.f, 0.f};
            acc = __builtin_amdgcn_mfma_f32_16x16x32_bf16(aq0, b0, acc, 0, 0, 0);
            acc = __builtin_amdgcn_mfma_f32_16x16x32_bf16(aq1, b1, acc, 0, 0, 0);
            st[t] = acc;
        }
        // scale into log2 domain + causal mask (diagonal tile only)
        float z[4][4];
        #pragma unroll
        for (int t = 0; t < 4; t++)
            #pragma unroll
            for (int r = 0; r < 4; r++) z[t][r] = st[t][r] * C2;
        if (jt == qt) {
            #pragma unroll
            for (int t = 0; t < 4; t++)
                #pragma unroll
                for (int r = 0; r < 4; r++)
                    if (t * 16 + cl > w * 16 + quad * 4 + r) z[t][r] = -1e30f;
        }
        // online softmax: rows live across the 16 lanes of each quad
        float rmax[4], alpha[4], psum[4], p[4][4];
        #pragma unroll
        for (int r = 0; r < 4; r++) {
            float v = fmaxf(fmaxf(z[0][r], z[1][r]), fmaxf(z[2][r], z[3][r]));
            v = fmaxf(v, __shfl_xor(v, 1, 64));
            v = fmaxf(v, __shfl_xor(v, 2, 64));
            v = fmaxf(v, __shfl_xor(v, 4, 64));
            v = fmaxf(v, __shfl_xor(v, 8, 64));
            rmax[r] = v;
        }
        #pragma unroll
        for (int r = 0; r < 4; r++) {
            float mn = fmaxf(mrow[r], rmax[r]);
            alpha[r] = exp2f(mrow[r] - mn);
            mrow[r] = mn;
        }
        #pragma unroll
        for (int t = 0; t < 4; t++)
            #pragma unroll
            for (int r = 0; r < 4; r++) p[t][r] = exp2f(z[t][r] - mrow[r]);
        #pragma unroll
        for (int r = 0; r < 4; r++) {
            float s = (p[0][r] + p[1][r]) + (p[2][r] + p[3][r]);
            s += __shfl_xor(s, 1, 64);
            s += __shfl_xor(s, 2, 64);
            s += __shfl_xor(s, 4, 64);
            s += __shfl_xor(s, 8, 64);
            psum[r] = s;
            lrow[r] = lrow[r] * alpha[r] + psum[r];
        }
        #pragma unroll
        for (int u = 0; u < 4; u++)
            #pragma unroll
            for (int r = 0; r < 4; r++) Oacc[u][r] *= alpha[r];

        // P: C-layout -> A-layout via per-wave LDS round-trip
        unsigned short* Pw = Ps[w];
        #pragma unroll
        for (int t = 0; t < 4; t++)
            #pragma unroll
            for (int r = 0; r < 4; r++)
                Pw[(quad * 4 + r) * 72 + t * 16 + cl] = f2bf(p[t][r]);
        __syncthreads();  // conservative: guarantee LDS write->read ordering

        bf16x8 ap0 = *(const bf16x8*)(const void*)(Pw + cl * 72 + quad * 8);
        bf16x8 ap1 = *(const bf16x8*)(const void*)(Pw + cl * 72 + 32 + quad * 8);
        #pragma unroll
        for (int u = 0; u < 4; u++) {
            bf16x8 bv0 = *(const bf16x8*)(const void*)(Vs + (u * 16 + cl) * 72 + quad * 8);
            bf16x8 bv1 = *(const bf16x8*)(const void*)(Vs + (u * 16 + cl) * 72 + 32 + quad * 8);
            Oacc[u] = __builtin_amdgcn_mfma_f32_16x16x32_bf16(ap0, bv0, Oacc[u], 0, 0, 0);
            Oacc[u] = __builtin_amdgcn_mfma_f32_16x16x32_bf16(ap1, bv1, Oacc[u], 0, 0, 0);
        }
    }
    // epilogue: normalize and store O fp32 [row][64]
    const size_t orow0 = (size_t)b * S_LEN + q0 + w * 16;
    #pragma unroll
    for (int r = 0; r < 4; r++) {
        float inv = 1.0f / lrow[r];
        #pragma unroll
        for (int u = 0; u < 4; u++)
            Ous[(orow0 + quad * 4 + r) * 64 + u * 16 + cl] = Oacc[u][r] * inv;
    }
}

// ---------------- K3: out = O @ Wo + bo (fp32)
__global__ __launch_bounds__(256) void oproj_kernel(
    const float* __restrict__ Ous, const float* __restrict__ Wo,
    const float* __restrict__ bo, float* __restrict__ out)
{
    __shared__ float os[16 * 64];
    const int tid = threadIdx.x;
    const size_t row0 = (size_t)blockIdx.x * 16;
    ((float4*)os)[tid] = ((const float4*)(Ous + row0 * 64))[tid];
    __syncthreads();
    const int w = tid >> 6, lane = tid & 63;
    float acc[4][8];
    #pragma unroll
    for (int r = 0; r < 4; r++)
        #pragma unroll
        for (int c = 0; c < 8; c++) acc[r][c] = 0.f;
    const float* orow = os + (w * 4) * 64;
    #pragma unroll 4
    for (int kk = 0; kk < 64; kk++) {
        float wv[8];
        #pragma unroll
        for (int c = 0; c < 8; c++) wv[c] = Wo[kk * 512 + c * 64 + lane];
        #pragma unroll
        for (int r = 0; r < 4; r++) {
            float ov = orow[r * 64 + kk];
            #pragma unroll
            for (int c = 0; c < 8; c++) acc[r][c] = fmaf(ov, wv[c], acc[r][c]);
        }
    }
    #pragma unroll
    for (int r = 0; r < 4; r++)
        #pragma unroll
        for (int c = 0; c < 8; c++)
            out[(row0 + w * 4 + r) * 512 + c * 64 + lane] = acc[r][c] + bo[c * 64 + lane];
}

extern "C" void kernel_launch(void* const* d_in, const int* in_sizes, int n_in,
                              void* d_out, int out_size, void* d_ws, size_t ws_size,
                              hipStream_t stream) {
    const float* x  = (const float*)d_in[0];
    const float* Wq = (const float*)d_in[1];
    const float* bq = (const float*)d_in[2];
    const float* Wk = (const float*)d_in[3];
    const float* bk = (const float*)d_in[4];
    const float* Wv = (const float*)d_in[5];
    const float* bv = (const float*)d_in[6];
    const float* Wo = (const float*)d_in[7];
    const float* bo = (const float*)d_in[8];
    float* out = (float*)d_out;

    char* ws = (char*)d_ws;
    unsigned short* Qb = (unsigned short*)ws;                 // 16384*64 bf16 = 2 MB
    unsigned short* Kb = Qb + (size_t)NROWS * 64;             // 2 MB
    unsigned short* Vt = Kb + (size_t)NROWS * 64;             // 2 MB (transposed [b][64][s])
    float* Ous = (float*)(ws + (size_t)3 * NROWS * 64 * 2);   // 4 MB fp32

    qkv_kernel<<<NROWS / 16, 256, 0, stream>>>(x, Wq, bq, Wk, bk, Wv, bv, Qb, Kb, Vt);
    attn_kernel<<<dim3(64, 4), 256, 0, stream>>>(Qb, Kb, Vt, Ous);
    oproj_kernel<<<NROWS / 16, 256, 0, stream>>>(Ous, Wo, bo, out);
}

// Round 2
// 210.185 us; speedup vs baseline: 1.3564x; 1.3564x over previous
//
#include <hip/hip_runtime.h>

#define S_LEN 4096
#define NROWS 16384   // B*S

typedef __attribute__((ext_vector_type(8))) __bf16 bf16x8;
typedef __attribute__((ext_vector_type(8))) unsigned short ushort8;
typedef __attribute__((ext_vector_type(4))) float floatx4;

__device__ __forceinline__ unsigned short f2bf(float f) {
    unsigned int u = __float_as_uint(f);
    unsigned int r = (u + 0x7fffu + ((u >> 16) & 1u)) >> 16;
    return (unsigned short)r;
}

__device__ __forceinline__ bf16x8 cvt_bf16x8(float4 a, float4 b) {
    union { ushort8 u; bf16x8 v; } r;
    r.u[0] = f2bf(a.x); r.u[1] = f2bf(a.y); r.u[2] = f2bf(a.z); r.u[3] = f2bf(a.w);
    r.u[4] = f2bf(b.x); r.u[5] = f2bf(b.y); r.u[6] = f2bf(b.z); r.u[7] = f2bf(b.w);
    return r.v;
}

// ---------------- K0: weights fp32 -> bf16 transposed (B-fragment-friendly)
// WqT/WkT/WvT: [64 out][512 k], WoT: [512 out][64 k]
__global__ __launch_bounds__(256) void convw_kernel(
    const float* __restrict__ Wq, const float* __restrict__ Wk,
    const float* __restrict__ Wv, const float* __restrict__ Wo,
    unsigned short* __restrict__ WqT, unsigned short* __restrict__ WkT,
    unsigned short* __restrict__ WvT, unsigned short* __restrict__ WoT)
{
    int tid = blockIdx.x * 256 + threadIdx.x;   // 0..32767
    int n = tid >> 9, k = tid & 511;            // (n<64, k<512)
    WqT[tid] = f2bf(Wq[k * 64 + n]);
    WkT[tid] = f2bf(Wk[k * 64 + n]);
    WvT[tid] = f2bf(Wv[k * 64 + n]);
    int n2 = tid >> 6, k2 = tid & 63;           // (n2<512, k2<64)
    WoT[tid] = f2bf(Wo[k2 * 512 + n2]);
}

// ---------------- K1: QKV projection via MFMA. 1 wave = 16 rows.
__global__ __launch_bounds__(64) void qkv_kernel(
    const float* __restrict__ x,
    const unsigned short* __restrict__ WqT, const unsigned short* __restrict__ WkT,
    const unsigned short* __restrict__ WvT,
    const float* __restrict__ bq, const float* __restrict__ bk, const float* __restrict__ bv,
    unsigned short* __restrict__ Qb, unsigned short* __restrict__ Kb,
    unsigned short* __restrict__ Vt)
{
    const int row0 = blockIdx.x * 16;
    const int lane = threadIdx.x, cl = lane & 15, quad = lane >> 4;
    floatx4 aQ[4], aK[4], aV[4];
    #pragma unroll
    for (int t = 0; t < 4; t++) { aQ[t] = (floatx4){0,0,0,0}; aK[t] = (floatx4){0,0,0,0}; aV[t] = (floatx4){0,0,0,0}; }
    const float* xrow = x + (size_t)(row0 + cl) * 512;
    #pragma unroll 2
    for (int kc = 0; kc < 16; kc++) {
        const int k0 = kc * 32 + quad * 8;
        float4 xa = *(const float4*)(xrow + k0);
        float4 xb = *(const float4*)(xrow + k0 + 4);
        bf16x8 af = cvt_bf16x8(xa, xb);
        #pragma unroll
        for (int t = 0; t < 4; t++) {
            bf16x8 bQ = *(const bf16x8*)(const void*)(WqT + (t * 16 + cl) * 512 + k0);
            bf16x8 bK = *(const bf16x8*)(const void*)(WkT + (t * 16 + cl) * 512 + k0);
            bf16x8 bV = *(const bf16x8*)(const void*)(WvT + (t * 16 + cl) * 512 + k0);
            aQ[t] = __builtin_amdgcn_mfma_f32_16x16x32_bf16(af, bQ, aQ[t], 0, 0, 0);
            aK[t] = __builtin_amdgcn_mfma_f32_16x16x32_bf16(af, bK, aK[t], 0, 0, 0);
            aV[t] = __builtin_amdgcn_mfma_f32_16x16x32_bf16(af, bV, aV[t], 0, 0, 0);
        }
    }
    const int b = row0 >> 12, s_base = row0 & 4095;
    #pragma unroll
    for (int t = 0; t < 4; t++) {
        const int d = t * 16 + cl;
        const float bqd = bq[d], bkd = bk[d], bvd = bv[d];
        #pragma unroll
        for (int r = 0; r < 4; r++) {
            const int rr = quad * 4 + r;
            Qb[(size_t)(row0 + rr) * 64 + d] = f2bf(aQ[t][r] + bqd);
            Kb[(size_t)(row0 + rr) * 64 + d] = f2bf(aK[t][r] + bkd);
            Vt[((size_t)b * 64 + d) * S_LEN + s_base + rr] = f2bf(aV[t][r] + bvd);
        }
    }
}

// ---------------- K2: causal flash attention, 16-row q-tiles, intra-block split-K.
// 4 waves/block share one q-tile; wave w handles key-tiles w, w+4, ... (no barriers
// in the K-loop); final (m,l,O) merge via LDS.
__global__ __launch_bounds__(256, 4) void attn_kernel(
    const unsigned short* __restrict__ Qb, const unsigned short* __restrict__ Kb,
    const unsigned short* __restrict__ Vt, unsigned short* __restrict__ Ob)
{
    __shared__ unsigned short Ps[4][16 * 72];
    __shared__ float Op[4][16][66];   // pad 66: quads land on distinct banks
    __shared__ float Ml[4][16][2];
    const int bid = blockIdx.x;              // 0..1023
    const int qt = 255 - (bid >> 2);         // longest-first (LPT)
    const int b = bid & 3;
    const int q0 = qt * 16;
    const int nkt = (qt >> 2) + 1;           // 64-key tiles in causal range
    const int tid = threadIdx.x;
    const int w = tid >> 6, lane = tid & 63, cl = lane & 15, quad = lane >> 4;

    const size_t qrow = (size_t)b * S_LEN + q0 + cl;
    const bf16x8 aq0 = *(const bf16x8*)(const void*)(Qb + qrow * 64 + quad * 8);
    const bf16x8 aq1 = *(const bf16x8*)(const void*)(Qb + qrow * 64 + 32 + quad * 8);

    float mrow[4], lrow[4];
    floatx4 Oacc[4];
    #pragma unroll
    for (int r = 0; r < 4; r++) { mrow[r] = -1e30f; lrow[r] = 0.f; }
    #pragma unroll
    for (int u = 0; u < 4; u++) Oacc[u] = (floatx4){0.f, 0.f, 0.f, 0.f};

    const float C2 = 0.022542110013890054f;  // log2(e)/sqrt(4096)
    unsigned short* Pw = Ps[w];

    for (int jt = w; jt < nkt; jt += 4) {
        const int j0 = jt * 64;
        // S = Q @ K^T, fragments direct from global (L2-resident)
        float z[4][4];
        #pragma unroll
        for (int t = 0; t < 4; t++) {
            const unsigned short* kp = Kb + ((size_t)b * S_LEN + j0 + t * 16 + cl) * 64 + quad * 8;
            bf16x8 b0 = *(const bf16x8*)(const void*)kp;
            bf16x8 b1 = *(const bf16x8*)(const void*)(kp + 32);
            floatx4 acc = (floatx4){0.f, 0.f, 0.f, 0.f};
            acc = __builtin_amdgcn_mfma_f32_16x16x32_bf16(aq0, b0, acc, 0, 0, 0);
            acc = __builtin_amdgcn_mfma_f32_16x16x32_bf16(aq1, b1, acc, 0, 0, 0);
            #pragma unroll
            for (int r = 0; r < 4; r++) z[t][r] = acc[r] * C2;
        }
        if (jt == nkt - 1) {  // only the last tile crosses the diagonal
            #pragma unroll
            for (int t = 0; t < 4; t++)
                #pragma unroll
                for (int r = 0; r < 4; r++)
                    if (j0 + t * 16 + cl > q0 + quad * 4 + r) z[t][r] = -1e30f;
        }
        // online softmax (rows live across the 16 cl-lanes of each quad)
        float alpha[4], p[4][4];
        #pragma unroll
        for (int r = 0; r < 4; r++) {
            float v = fmaxf(fmaxf(z[0][r], z[1][r]), fmaxf(z[2][r], z[3][r]));
            v = fmaxf(v, __shfl_xor(v, 1, 64));
            v = fmaxf(v, __shfl_xor(v, 2, 64));
            v = fmaxf(v, __shfl_xor(v, 4, 64));
            v = fmaxf(v, __shfl_xor(v, 8, 64));
            float mn = fmaxf(mrow[r], v);
            alpha[r] = exp2f(mrow[r] - mn);
            mrow[r] = mn;
        }
        #pragma unroll
        for (int t = 0; t < 4; t++)
            #pragma unroll
            for (int r = 0; r < 4; r++) p[t][r] = exp2f(z[t][r] - mrow[r]);
        #pragma unroll
        for (int r = 0; r < 4; r++) {
            float s = (p[0][r] + p[1][r]) + (p[2][r] + p[3][r]);
            s += __shfl_xor(s, 1, 64);
            s += __shfl_xor(s, 2, 64);
            s += __shfl_xor(s, 4, 64);
            s += __shfl_xor(s, 8, 64);
            lrow[r] = lrow[r] * alpha[r] + s;
        }
        #pragma unroll
        for (int u = 0; u < 4; u++)
            #pragma unroll
            for (int r = 0; r < 4; r++) Oacc[u][r] *= alpha[r];

        // P: C-layout -> A-layout via wave-local LDS (no __syncthreads: trip
        // counts differ per wave; s_waitcnt orders the wave's own LDS ops)
        #pragma unroll
        for (int t = 0; t < 4; t++)
            #pragma unroll
            for (int r = 0; r < 4; r++)
                Pw[(quad * 4 + r) * 72 + t * 16 + cl] = f2bf(p[t][r]);
        asm volatile("s_waitcnt lgkmcnt(0)" ::: "memory");
        bf16x8 ap0 = *(const bf16x8*)(const void*)(Pw + cl * 72 + quad * 8);
        bf16x8 ap1 = *(const bf16x8*)(const void*)(Pw + cl * 72 + 32 + quad * 8);
        #pragma unroll
        for (int u = 0; u < 4; u++) {
            const unsigned short* vp = Vt + ((size_t)b * 64 + u * 16 + cl) * S_LEN + j0 + quad * 8;
            bf16x8 bv0 = *(const bf16x8*)(const void*)vp;
            bf16x8 bv1 = *(const bf16x8*)(const void*)(vp + 32);
            Oacc[u] = __builtin_amdgcn_mfma_f32_16x16x32_bf16(ap0, bv0, Oacc[u], 0, 0, 0);
            Oacc[u] = __builtin_amdgcn_mfma_f32_16x16x32_bf16(ap1, bv1, Oacc[u], 0, 0, 0);
        }
    }
    // publish partials
    #pragma unroll
    for (int u = 0; u < 4; u++)
        #pragma unroll
        for (int r = 0; r < 4; r++)
            Op[w][quad * 4 + r][u * 16 + cl] = Oacc[u][r];
    if (cl == 0) {
        #pragma unroll
        for (int r = 0; r < 4; r++) {
            Ml[w][quad * 4 + r][0] = mrow[r];
            Ml[w][quad * 4 + r][1] = lrow[r];
        }
    }
    __syncthreads();
    // merge 4 partials: thread -> (row, 4 consecutive d)
    {
        const int row = tid >> 4, d0 = (tid & 15) * 4;
        float m0 = Ml[0][row][0], m1 = Ml[1][row][0], m2 = Ml[2][row][0], m3 = Ml[3][row][0];
        float M = fmaxf(fmaxf(m0, m1), fmaxf(m2, m3));
        float s0 = exp2f(m0 - M), s1 = exp2f(m1 - M), s2 = exp2f(m2 - M), s3 = exp2f(m3 - M);
        float L = s0 * Ml[0][row][1] + s1 * Ml[1][row][1] + s2 * Ml[2][row][1] + s3 * Ml[3][row][1];
        float invL = 1.0f / L;
        unsigned short ov[4];
        #pragma unroll
        for (int i = 0; i < 4; i++) {
            float o = s0 * Op[0][row][d0 + i] + s1 * Op[1][row][d0 + i]
                    + s2 * Op[2][row][d0 + i] + s3 * Op[3][row][d0 + i];
            ov[i] = f2bf(o * invL);
        }
        *(uint2*)(void*)(Ob + ((size_t)b * S_LEN + q0 + row) * 64 + d0) = *(const uint2*)ov;
    }
}

// ---------------- K3: out = O @ Wo + bo via MFMA. 1 wave = 16 rows x 512 cols.
__global__ __launch_bounds__(64) void oproj_kernel(
    const unsigned short* __restrict__ Ob, const unsigned short* __restrict__ WoT,
    const float* __restrict__ bo, float* __restrict__ out)
{
    const int row0 = blockIdx.x * 16;
    const int lane = threadIdx.x, cl = lane & 15, quad = lane >> 4;
    const unsigned short* op = Ob + (size_t)(row0 + cl) * 64 + quad * 8;
    const bf16x8 a0 = *(const bf16x8*)(const void*)op;
    const bf16x8 a1 = *(const bf16x8*)(const void*)(op + 32);
    #pragma unroll 4
    for (int ct = 0; ct < 32; ct++) {
        const unsigned short* wp = WoT + (ct * 16 + cl) * 64 + quad * 8;
        bf16x8 b0 = *(const bf16x8*)(const void*)wp;
        bf16x8 b1 = *(const bf16x8*)(const void*)(wp + 32);
        floatx4 acc = (floatx4){0.f, 0.f, 0.f, 0.f};
        acc = __builtin_amdgcn_mfma_f32_16x16x32_bf16(a0, b0, acc, 0, 0, 0);
        acc = __builtin_amdgcn_mfma_f32_16x16x32_bf16(a1, b1, acc, 0, 0, 0);
        const float bod = bo[ct * 16 + cl];
        #pragma unroll
        for (int r = 0; r < 4; r++)
            out[(size_t)(row0 + quad * 4 + r) * 512 + ct * 16 + cl] = acc[r] + bod;
    }
}

extern "C" void kernel_launch(void* const* d_in, const int* in_sizes, int n_in,
                              void* d_out, int out_size, void* d_ws, size_t ws_size,
                              hipStream_t stream) {
    const float* x  = (const float*)d_in[0];
    const float* Wq = (const float*)d_in[1];
    const float* bq = (const float*)d_in[2];
    const float* Wk = (const float*)d_in[3];
    const float* bk = (const float*)d_in[4];
    const float* Wv = (const float*)d_in[5];
    const float* bv = (const float*)d_in[6];
    const float* Wo = (const float*)d_in[7];
    const float* bo = (const float*)d_in[8];
    float* out = (float*)d_out;

    unsigned short* Qb  = (unsigned short*)d_ws;               // 2 MB
    unsigned short* Kb  = Qb + (size_t)NROWS * 64;             // 2 MB
    unsigned short* Vt  = Kb + (size_t)NROWS * 64;             // 2 MB (transposed [b][64][s])
    unsigned short* Ob  = Vt + (size_t)NROWS * 64;             // 2 MB (bf16 O, row-major)
    unsigned short* WqT = Ob + (size_t)NROWS * 64;             // 64 KB each
    unsigned short* WkT = WqT + 512 * 64;
    unsigned short* WvT = WkT + 512 * 64;
    unsigned short* WoT = WvT + 512 * 64;

    convw_kernel<<<128, 256, 0, stream>>>(Wq, Wk, Wv, Wo, WqT, WkT, WvT, WoT);
    qkv_kernel<<<NROWS / 16, 64, 0, stream>>>(x, WqT, WkT, WvT, bq, bk, bv, Qb, Kb, Vt);
    attn_kernel<<<1024, 256, 0, stream>>>(Qb, Kb, Vt, Ob);
    oproj_kernel<<<NROWS / 16, 64, 0, stream>>>(Ob, WoT, bo, out);
}